// Round 1
// baseline (734.258 us; speedup 1.0000x reference)
//
#include <hip/hip_runtime.h>

#define N_ 20000
#define E_ 100000

typedef __attribute__((ext_vector_type(8))) short short8;
typedef __attribute__((ext_vector_type(8))) unsigned short ushort8;
typedef __attribute__((ext_vector_type(4))) float f32x4;

__device__ __forceinline__ unsigned short f2bf(float f) {
  union { float f; unsigned u; } v; v.f = f;
  unsigned r = v.u + 0x7fffu + ((v.u >> 16) & 1u);
  return (unsigned short)(r >> 16);
}
__device__ __forceinline__ float bf2f(unsigned short h) {
  union { unsigned u; float f; } v; v.u = ((unsigned)h) << 16;
  return v.f;
}

// ---------------- K1: h2 = relu(edge_attr @ e1_w.T + e1_b), bf16 [E][128]
__global__ __launch_bounds__(256) void k_h2(const float* __restrict__ ea,
                                            const float* __restrict__ e1w,
                                            const float* __restrict__ e1b,
                                            unsigned short* __restrict__ h2) {
  int id = blockIdx.x * 256 + threadIdx.x;  // id = e*128 + k
  int e = id >> 7, k = id & 127;
  if (e >= E_) return;
  const float4* ar = (const float4*)(ea + e * 16);
  const float4* wr = (const float4*)(e1w + k * 16);
  float acc = e1b[k];
#pragma unroll
  for (int q = 0; q < 4; ++q) {
    float4 a = ar[q], w = wr[q];
    acc += a.x * w.x + a.y * w.y + a.z * w.z + a.w * w.w;
  }
  h2[id] = f2bf(fmaxf(acc, 0.f));
}

// ---------------- K2: pre-swizzle Bmat[k][c]=e2_w[c][k] into MFMA B-fragment order
// Bf[((kf*256+cf)*64 + l)*8 + r] = bf16(e2w[(cf*16+(l&15))*128 + kf*32 + (l>>4)*8 + r])
__global__ __launch_bounds__(256) void k_prep_bf(const float* __restrict__ e2w,
                                                 unsigned short* __restrict__ Bf) {
  int tid = blockIdx.x * 256 + threadIdx.x;  // 65536 threads
  int l = tid & 63, cf = (tid >> 6) & 255, kf = tid >> 14;
  int g = l >> 4, lm = l & 15;
  const float* src = e2w + (cf * 16 + lm) * 128 + kf * 32 + g * 8;
  float4 s0 = *(const float4*)(src);
  float4 s1 = *(const float4*)(src + 4);
  ushort8 v;
  v[0] = f2bf(s0.x); v[1] = f2bf(s0.y); v[2] = f2bf(s0.z); v[3] = f2bf(s0.w);
  v[4] = f2bf(s1.x); v[5] = f2bf(s1.y); v[6] = f2bf(s1.z); v[7] = f2bf(s1.w);
  *(ushort8*)(Bf + (size_t)tid * 8) = v;
}

// ---------------- K3: out0 = relu(nf @ mp_w.T + mp_b); y0 = out0 @ e2bmat
__global__ __launch_bounds__(256) void k_node_in(const float* __restrict__ nfm,
                                                 const float* __restrict__ mpw,
                                                 const float* __restrict__ mpb,
                                                 const float* __restrict__ e2b,
                                                 float* __restrict__ outc,
                                                 float* __restrict__ yc) {
  __shared__ float wT[64 * 65];
  __shared__ float xr[4 * 65];
  __shared__ float nr[4 * 65];
  int t = threadIdx.x;
  for (int idx = t; idx < 4096; idx += 256) {
    int o = idx >> 6, i = idx & 63;
    wT[i * 65 + o] = mpw[idx];  // mp_w[o][i]
  }
  __syncthreads();
  int nl = t >> 6, o = t & 63;
  for (int it = 0; it < 4; ++it) {
    int n = blockIdx.x * 16 + it * 4 + nl;
    xr[nl * 65 + o] = nfm[n * 64 + o];
    __syncthreads();
    float acc = mpb[o];
#pragma unroll 8
    for (int i = 0; i < 64; ++i) acc += xr[nl * 65 + i] * wT[i * 65 + o];
    float m = fmaxf(acc, 0.f);
    outc[n * 64 + o] = m;
    nr[nl * 65 + o] = m;
    __syncthreads();
    float yv = 0.f;
#pragma unroll 8
    for (int j = 0; j < 64; ++j) yv += nr[nl * 65 + j] * e2b[j * 64 + o];
    yc[n * 64 + o] = yv;
    __syncthreads();
  }
}

// ---------------- zero kernel
__global__ void k_zero(float* __restrict__ p, int n) {
  int i = blockIdx.x * 256 + threadIdx.x;
  if (i < n) p[i] = 0.f;
}

// ---------------- K5: fused msgs + scatter.
// Block: 64 edges, 4 waves; wave w handles i in [16w,16w+16).
// Per i: D[e, i*64+o] = sum_k h2[e,k]*e2wT[k, i*64+o] via MFMA; fold msgs += x[e,i]*D.
__global__ __launch_bounds__(256, 2) void k_msgs(const float* __restrict__ x,
                                                 const float* __restrict__ y,
                                                 const unsigned short* __restrict__ h2,
                                                 const unsigned short* __restrict__ Bf,
                                                 const int* __restrict__ ei,
                                                 float* __restrict__ agg) {
  __shared__ float xT[64 * 65];              // x transposed [i][e], padded
  __shared__ unsigned short pm[4][64 * 66];  // per-wave bf16 partial msgs
  __shared__ int sidx[64];
  __shared__ int didx[64];
  int t = threadIdx.x, w = t >> 6, l = t & 63;
  int e0 = blockIdx.x * 64;
  if (t < 64) {
    int e = e0 + t;
    sidx[t] = (e < E_) ? ei[e] : 0;
    didx[t] = (e < E_) ? ei[E_ + e] : -1;
  }
  __syncthreads();
  // gather x rows -> xT (transposed, padded: conflict-free)
  for (int it = 0; it < 16; ++it) {
    int idx = it * 256 + t;
    int e = idx >> 6, i = idx & 63;
    xT[i * 65 + e] = x[sidx[e] * 64 + i];
  }
  // A fragments: h2 rows for all 64 edges, resident in VGPRs
  int g = l >> 4, lm = l & 15;
  short8 af[4][4];
#pragma unroll
  for (int mf = 0; mf < 4; ++mf) {
    int e = e0 + mf * 16 + lm;
    if (e >= E_) e = E_ - 1;
    const short8* hp = (const short8*)(h2 + (size_t)e * 128 + g * 8);
    af[mf][0] = hp[0]; af[mf][1] = hp[4]; af[mf][2] = hp[8]; af[mf][3] = hp[12];
  }
  __syncthreads();  // xT ready
  f32x4 macc[4][4];
#pragma unroll
  for (int mf = 0; mf < 4; ++mf)
#pragma unroll
    for (int nf = 0; nf < 4; ++nf) macc[mf][nf] = f32x4{0.f, 0.f, 0.f, 0.f};

  for (int il = 0; il < 16; ++il) {
    int i = w * 16 + il;
    f32x4 dacc[4][4];
#pragma unroll
    for (int mf = 0; mf < 4; ++mf)
#pragma unroll
      for (int nf = 0; nf < 4; ++nf) dacc[mf][nf] = f32x4{0.f, 0.f, 0.f, 0.f};
    const short8* bp = (const short8*)Bf + (i * 4) * 64 + l;
#pragma unroll
    for (int kf = 0; kf < 4; ++kf) {
      short8 b0 = bp[kf * 16384 + 0];
      short8 b1 = bp[kf * 16384 + 64];
      short8 b2 = bp[kf * 16384 + 128];
      short8 b3 = bp[kf * 16384 + 192];
#pragma unroll
      for (int mf = 0; mf < 4; ++mf) {
        dacc[mf][0] = __builtin_amdgcn_mfma_f32_16x16x32_bf16(af[mf][kf], b0, dacc[mf][0], 0, 0, 0);
        dacc[mf][1] = __builtin_amdgcn_mfma_f32_16x16x32_bf16(af[mf][kf], b1, dacc[mf][1], 0, 0, 0);
        dacc[mf][2] = __builtin_amdgcn_mfma_f32_16x16x32_bf16(af[mf][kf], b2, dacc[mf][2], 0, 0, 0);
        dacc[mf][3] = __builtin_amdgcn_mfma_f32_16x16x32_bf16(af[mf][kf], b3, dacc[mf][3], 0, 0, 0);
      }
    }
    // fold: msgs[e,o] += x[e,i] * D[e,o]   (D row e = mf*16 + g*4 + r)
#pragma unroll
    for (int mf = 0; mf < 4; ++mf) {
      float xs0 = xT[i * 65 + mf * 16 + g * 4 + 0];
      float xs1 = xT[i * 65 + mf * 16 + g * 4 + 1];
      float xs2 = xT[i * 65 + mf * 16 + g * 4 + 2];
      float xs3 = xT[i * 65 + mf * 16 + g * 4 + 3];
#pragma unroll
      for (int nf = 0; nf < 4; ++nf) {
        macc[mf][nf][0] += xs0 * dacc[mf][nf][0];
        macc[mf][nf][1] += xs1 * dacc[mf][nf][1];
        macc[mf][nf][2] += xs2 * dacc[mf][nf][2];
        macc[mf][nf][3] += xs3 * dacc[mf][nf][3];
      }
    }
  }
  // write per-wave partials (bf16) to LDS
#pragma unroll
  for (int mf = 0; mf < 4; ++mf)
#pragma unroll
    for (int nf = 0; nf < 4; ++nf)
#pragma unroll
      for (int r = 0; r < 4; ++r) {
        int e = mf * 16 + g * 4 + r, o = nf * 16 + lm;
        pm[w][e * 66 + o] = f2bf(macc[mf][nf][r]);
      }
  __syncthreads();
  // reduce 4 waves + e2_b rank-1 term (y[src]) + scatter-add
  for (int it = 0; it < 16; ++it) {
    int idx = it * 256 + t;
    int e = idx >> 6, o = idx & 63;
    int d = didx[e];
    if (d >= 0) {
      float v = bf2f(pm[0][e * 66 + o]) + bf2f(pm[1][e * 66 + o]) +
                bf2f(pm[2][e * 66 + o]) + bf2f(pm[3][e * 66 + o]);
      v += y[sidx[e] * 64 + o];
      atomicAdd(agg + (size_t)d * 64 + o, v);
    }
  }
}

// ---------------- K6: node update
// m = relu(agg + out@root + conv_b); out' = [m,out]@msg_w.T + msg_b; y' = out'@e2bmat
__global__ __launch_bounds__(256) void k_update(const float* __restrict__ outc,
                                                const float* __restrict__ agg,
                                                const float* __restrict__ root,
                                                const float* __restrict__ convb,
                                                const float* __restrict__ msgw,
                                                const float* __restrict__ msgb,
                                                const float* __restrict__ e2b,
                                                const float* __restrict__ nfm,
                                                int last,
                                                float* __restrict__ outn,
                                                float* __restrict__ yn,
                                                float* __restrict__ dout) {
  __shared__ float wT[128 * 65];
  __shared__ float xr[4 * 65];
  __shared__ float mr[4 * 65];
  __shared__ float nr[4 * 65];
  int t = threadIdx.x;
  for (int idx = t; idx < 8192; idx += 256) {
    int o = idx >> 7, j = idx & 127;
    wT[j * 65 + o] = msgw[idx];  // msg_w[o][j]
  }
  __syncthreads();
  int nl = t >> 6, o = t & 63;
  for (int it = 0; it < 4; ++it) {
    int n = blockIdx.x * 16 + it * 4 + nl;
    xr[nl * 65 + o] = outc[n * 64 + o];
    __syncthreads();
    float acc = agg[n * 64 + o] + convb[o];
#pragma unroll 8
    for (int i = 0; i < 64; ++i) acc += xr[nl * 65 + i] * root[i * 64 + o];
    float m = fmaxf(acc, 0.f);
    mr[nl * 65 + o] = m;
    __syncthreads();
    float o2 = msgb[o];
#pragma unroll 8
    for (int j = 0; j < 64; ++j)
      o2 += mr[nl * 65 + j] * wT[j * 65 + o] + xr[nl * 65 + j] * wT[(64 + j) * 65 + o];
    nr[nl * 65 + o] = o2;
    __syncthreads();
    if (last) {
      dout[n * 64 + o] = o2 + nfm[n * 64 + o];
    } else {
      float yv = 0.f;
#pragma unroll 8
      for (int j = 0; j < 64; ++j) yv += nr[nl * 65 + j] * e2b[j * 64 + o];
      outn[n * 64 + o] = o2;
      yn[n * 64 + o] = yv;
    }
    __syncthreads();
  }
}

extern "C" void kernel_launch(void* const* d_in, const int* in_sizes, int n_in,
                              void* d_out, int out_size, void* d_ws, size_t ws_size,
                              hipStream_t stream) {
  const float* nfm  = (const float*)d_in[0];
  const float* ea   = (const float*)d_in[1];
  const int*   ei   = (const int*)d_in[2];
  const float* mpw  = (const float*)d_in[3];
  const float* mpb  = (const float*)d_in[4];
  const float* msgw = (const float*)d_in[5];
  const float* msgb = (const float*)d_in[6];
  const float* e1w  = (const float*)d_in[7];
  const float* e1b  = (const float*)d_in[8];
  const float* e2w  = (const float*)d_in[9];
  const float* e2b  = (const float*)d_in[10];
  const float* root = (const float*)d_in[11];
  const float* convb= (const float*)d_in[12];
  float* out = (float*)d_out;

  char* ws = (char*)d_ws;
  unsigned short* h2 = (unsigned short*)ws; ws += (size_t)E_ * 128 * 2;
  unsigned short* Bf = (unsigned short*)ws; ws += (size_t)4096 * 128 * 2;
  float* outa = (float*)ws; ws += (size_t)N_ * 64 * 4;
  float* ya   = (float*)ws; ws += (size_t)N_ * 64 * 4;
  float* outb = (float*)ws; ws += (size_t)N_ * 64 * 4;
  float* yb   = (float*)ws; ws += (size_t)N_ * 64 * 4;
  float* agg  = (float*)ws; ws += (size_t)N_ * 64 * 4;

  hipLaunchKernelGGL(k_prep_bf, dim3(256), dim3(256), 0, stream, e2w, Bf);
  hipLaunchKernelGGL(k_h2, dim3((E_ * 128) / 256), dim3(256), 0, stream, ea, e1w, e1b, h2);
  hipLaunchKernelGGL(k_node_in, dim3(N_ / 16), dim3(256), 0, stream, nfm, mpw, mpb, e2b, outa, ya);

  float* oc = outa; float* yc = ya; float* on = outb; float* yv = yb;
  for (int s = 0; s < 3; ++s) {
    hipLaunchKernelGGL(k_zero, dim3((N_ * 64 + 255) / 256), dim3(256), 0, stream, agg, N_ * 64);
    hipLaunchKernelGGL(k_msgs, dim3((E_ + 63) / 64), dim3(256), 0, stream, oc, yc, h2, Bf, ei, agg);
    hipLaunchKernelGGL(k_update, dim3(N_ / 16), dim3(256), 0, stream, oc, agg, root, convb,
                       msgw, msgb, e2b, nfm, (s == 2) ? 1 : 0, on, yv, out);
    float* tp;
    tp = oc; oc = on; on = tp;
    tp = yc; yc = yv; yv = tp;
  }
}